// Round 8
// baseline (222.666 us; speedup 1.0000x reference)
//
#include <hip/hip_runtime.h>
#include <hip/hip_bf16.h>

#define B_  16
#define LQ  2048
#define LS  2048
#define DD  512
#define BQ  256
#define BS  256
#define BK  64
#define HK  32            // half-K granularity of the prefetch ring
#define NSB (LS / BS)     // 8 s-blocks total
#define NKC (DD / BK)     // 8 k-stages per s-block
#define NSPLIT 4

static_assert(NKC == 8, "stage>>3 math assumes NKC==8");

typedef short bf16x8 __attribute__((ext_vector_type(8)));
typedef float f32x4  __attribute__((ext_vector_type(4)));

// async global->LDS, 16B per lane. LDS dest = wave-uniform base + lane*16.
__device__ __forceinline__ void load_lds16(const void* g, void* l) {
  __builtin_amdgcn_global_load_lds((const __attribute__((address_space(1))) void*)g,
                                   (__attribute__((address_space(3))) void*)l,
                                   16, 0, 0);
}

__device__ __forceinline__ unsigned short f2bf(float f) {
  union { float f; unsigned int u; } v; v.f = f;
  unsigned int r = v.u + 0x7fffu + ((v.u >> 16) & 1u);  // RNE
  return (unsigned short)(r >> 16);
}

// Grid-stride cvt: 2048 blocks (first half Q, second half S), 16 iters each.
__global__ __launch_bounds__(256) void cvt_kernel(const float* __restrict__ Q,
                                                  const float* __restrict__ S,
                                                  unsigned short* __restrict__ Qw,
                                                  unsigned short* __restrict__ Sw) {
  const int half = gridDim.x >> 1;
  int blk = blockIdx.x;
  const float* src; unsigned short* dst;
  if (blk < half) { src = Q; dst = Qw; } else { src = S; dst = Sw; blk -= half; }
  const size_t n4 = (size_t)B_ * LQ * DD / 4;
  const size_t stride = (size_t)half * 256;
  for (size_t i = (size_t)blk * 256 + threadIdx.x; i < n4; i += stride) {
    float4 f = ((const float4*)src)[i];
    ushort4 u;
    u.x = f2bf(f.x); u.y = f2bf(f.y); u.z = f2bf(f.z); u.w = f2bf(f.w);
    ((ushort4*)dst)[i] = u;
  }
}

// score[b,q] = sum_s softmax(l)[s]*l[s],  l[s] = Q[b,q,:].S[b,s,:]
// MFMA 16x16x32: A = S-tile (M=s), B = Q-tile^T (N=q) -> C[row=s][col=q]
// C layout: col = lane&15, row = (lane>>4)*4 + reg  [m89/m91]
//
// Round-8 = Round-7 resubmit (infra failure; kernel re-audited: uniform
// barriers, consistent vmcnt ledger, WAR/RAW safe, in-bounds). One change:
// __builtin_amdgcn_s_barrier() instead of raw asm s_barrier (matches the
// known-good pattern of all passing rounds; guarantees barrier metadata).
//
// True T3+T4 combo. R2 (counted, no phases), R4 (phases, drain0), R6
// (one-barrier drain) were all ~89-91us = the m218 null quadrants; the
// measured lever is the combo. Structure = m201 port at half-K granularity:
//  - 4-slot ring of K=32 halves (slot = u&3), 16KB Q + 16KB S each = 128 KiB
//  - steady state: 3 halves in flight, vmcnt(8) at pair top -- NEVER 0 in
//    the main loop; the only drains are prologue/last-2-iters
//  - one s_barrier per half (same barrier rate as R2, but no drain at it)
//  - per half: {vmcnt(8); barrier; issue 4 gl_lds (u+3); 8 ds_read; lgkm0;
//    16 MFMA; 4 ds_read; lgkm0; 16 MFMA} -- ds_read/gl_lds/MFMA interleave
//  - RAW: each wave vmcnt-waits its OWN 4 loads of half u pre-barrier ->
//    post-barrier all waves' loads of half u are in LDS.
//    WAR: slot (u+3)&3's prior readers (pair u-1) retired at their lgkm0
//    before this barrier; slot (u+3)&3 differs from u,u+1,u+2's slots.
//  - XOR swizzle (both sides): LDS slot j of row r holds global chunk
//    j^(r&3); read uses slot quad^(col&3); stage source chunk (l&3)^((l>>2)&3).
// Kept from R6: L2-locality lid decode (FETCH 147->33 MB), XCD chunk swizzle,
// grid-stride cvt.
__global__ __launch_bounds__(512, 2) void attn_kernel(const unsigned short* __restrict__ Qw,
                                                      const unsigned short* __restrict__ Sw,
                                                      float* __restrict__ out,
                                                      float* __restrict__ pm,
                                                      float* __restrict__ pse,
                                                      float* __restrict__ psel,
                                                      int nsplit) {
  // ring of 4 half-K slots, each 256 rows x 32 k x 2B = 16 KiB per tensor
  __shared__ __align__(16) unsigned short sQh[4][BQ * HK];  // 64 KiB
  __shared__ __align__(16) unsigned short sSh[4][BS * HK];  // 64 KiB

  // --- chunked XCD swizzle (bijective: nwg = 128*nsplit divisible by 8) ---
  const int pid = blockIdx.x + (blockIdx.y << 3) + (blockIdx.z << 7);
  const int nch = (nsplit << 7) >> 3;          // nwg / 8
  const int lid = (pid & 7) * nch + (pid >> 3);
  // locality decode: qb fastest, then spl, then b (per-XCD set ~4MB = L2)
  const int qb   = lid & 7;                    // gridDim.x == 8
  const int rest = lid >> 3;
  const int spl  = rest & (nsplit - 1);        // nsplit in {1,4}
  const int b    = rest >> (nsplit == 4 ? 2 : 0);

  const int tid  = threadIdx.x;
  const int w    = tid >> 6;      // 0..7
  const int lane = tid & 63;
  const int h    = w & 1;         // s-half: rows [h*128, h*128+128)
  const int g    = w >> 1;        // q-quarter: cols [g*64, g*64+64)
  const int col  = lane & 15;
  const int quad = lane >> 4;

  const int q0 = qb * BQ;
  const unsigned short* Qb = Qw + (size_t)b * LQ * DD;
  const unsigned short* Sb = Sw + (size_t)b * LS * DD;

  float mst[4] = { -INFINITY, -INFINITY, -INFINITY, -INFINITY };
  float se[4]  = { 0.f, 0.f, 0.f, 0.f };
  float sel[4] = { 0.f, 0.f, 0.f, 0.f };

  f32x4 acc[8][4];   // [s-tile][q-tile] = 128 regs (AGPR side of unified file)
#pragma unroll
  for (int st = 0; st < 8; ++st)
#pragma unroll
    for (int qt = 0; qt < 4; ++qt)
      acc[st][qt] = (f32x4){0.f, 0.f, 0.f, 0.f};

  // staging source chunk pre-swizzle: lane l -> row (l>>2), slot (l&3);
  // slot j of row r must hold global chunk j^(r&3) -> chunk = (l&3)^((l>>2)&3)
  const int cc8 = (((lane & 3) ^ ((lane >> 2) & 3)) * 8);
  const int rl  = lane >> 2;                 // row-within-16 for staging
  // read-side slot XOR: row&3 == col&3 for all frag rows (bases %16 == 0)
  const int koq = ((quad ^ (col & 3)) * 8);

  const int sbs = spl * (NSB / nsplit);
  const int nst = (NSB / nsplit) * NKC;      // stages (K=64)
  const int U   = nst * 2;                   // halves (K=32)

  // waves 0..3 stage Q rows [w*64,+64); waves 4..7 stage S rows [(w-4)*64,+64)
  // 4 loads/wave/half, each load = 16 consecutive rows x 32k (1 KiB linear).
  auto issue_half = [&](int u) {
    const int t  = u >> 1;
    const int k0 = (t & 7) * 64 + (u & 1) * 32;
    const int slot = u & 3;
    if (w < 4) {
      const unsigned short* gp = Qb + (size_t)(q0 + w * 64 + rl) * DD + k0 + cc8;
      unsigned short* lp = &sQh[slot][(w * 64) * HK];
#pragma unroll
      for (int i = 0; i < 4; ++i)
        load_lds16(gp + (size_t)i * 16 * DD, lp + i * 16 * HK);
    } else {
      const int sb = sbs + (t >> 3);
      const unsigned short* gp = Sb + (size_t)(sb * BS + (w - 4) * 64 + rl) * DD + k0 + cc8;
      unsigned short* lp = &sSh[slot][((w - 4) * 64) * HK];
#pragma unroll
      for (int i = 0; i < 4; ++i)
        load_lds16(gp + (size_t)i * 16 * DD, lp + i * 16 * HK);
    }
  };

  // prologue: fill 3 ring slots
  issue_half(0); issue_half(1); issue_half(2);

#pragma unroll 1
  for (int u = 0; u < U; ++u) {
    // pair-top wait: own 4 loads of half u retired (u+1,u+2 keep flying)
    if (u < U - 2)       asm volatile("s_waitcnt vmcnt(8)" ::: "memory");
    else if (u == U - 2) asm volatile("s_waitcnt vmcnt(4)" ::: "memory");
    else                 asm volatile("s_waitcnt vmcnt(0)" ::: "memory");
    __builtin_amdgcn_s_barrier();             // half u visible CU-wide
    if (u + 3 < U) issue_half(u + 3);

    const unsigned short* bq = &sQh[u & 3][0];
    const unsigned short* bs = &sSh[u & 3][0];

    bf16x8 aq[4], asv[4];
#pragma unroll
    for (int qt = 0; qt < 4; ++qt)
      aq[qt] = *(const bf16x8*)&bq[(g * 64 + qt * 16 + col) * HK + koq];
#pragma unroll
    for (int st = 0; st < 4; ++st)
      asv[st] = *(const bf16x8*)&bs[(h * 128 + st * 16 + col) * HK + koq];
    asm volatile("s_waitcnt lgkmcnt(0)" ::: "memory");
    __builtin_amdgcn_sched_barrier(0);
    __builtin_amdgcn_s_setprio(1);
#pragma unroll
    for (int qt = 0; qt < 4; ++qt)
#pragma unroll
      for (int st = 0; st < 4; ++st)
        acc[st][qt] = __builtin_amdgcn_mfma_f32_16x16x32_bf16(asv[st], aq[qt], acc[st][qt], 0, 0, 0);
    __builtin_amdgcn_s_setprio(0);

#pragma unroll
    for (int st = 0; st < 4; ++st)
      asv[st] = *(const bf16x8*)&bs[(h * 128 + (4 + st) * 16 + col) * HK + koq];
    asm volatile("s_waitcnt lgkmcnt(0)" ::: "memory");
    __builtin_amdgcn_sched_barrier(0);
    __builtin_amdgcn_s_setprio(1);
#pragma unroll
    for (int qt = 0; qt < 4; ++qt)
#pragma unroll
      for (int st = 0; st < 4; ++st)
        acc[4 + st][qt] = __builtin_amdgcn_mfma_f32_16x16x32_bf16(asv[st], aq[qt], acc[4 + st][qt], 0, 0, 0);
    __builtin_amdgcn_s_setprio(0);

    if ((u & (2 * NKC - 1)) == 2 * NKC - 1) {
      // online softmax-weighted-mean over this wave's 128-s rows; runs while
      // 3 halves of the next s-block are in flight (no barrier until pair top)
#pragma unroll
      for (int qt = 0; qt < 4; ++qt) {
        float lmax = mst[qt];
#pragma unroll
        for (int st = 0; st < 8; ++st)
#pragma unroll
          for (int r = 0; r < 4; ++r)
            lmax = fmaxf(lmax, acc[st][qt][r]);
        lmax = fmaxf(lmax, __shfl_xor(lmax, 16, 64));
        lmax = fmaxf(lmax, __shfl_xor(lmax, 32, 64));
        float alpha = __expf(mst[qt] - lmax);  // exp(-inf)=0 on first block
        float pe = 0.f, pel = 0.f;
#pragma unroll
        for (int st = 0; st < 8; ++st)
#pragma unroll
          for (int r = 0; r < 4; ++r) {
            float l = acc[st][qt][r];
            float e = __expf(l - lmax);
            pe += e;
            pel = fmaf(e, l, pel);
          }
        pe  += __shfl_xor(pe, 16, 64);  pe  += __shfl_xor(pe, 32, 64);
        pel += __shfl_xor(pel, 16, 64); pel += __shfl_xor(pel, 32, 64);
        se[qt]  = fmaf(se[qt],  alpha, pe);
        sel[qt] = fmaf(sel[qt], alpha, pel);
        mst[qt] = lmax;
#pragma unroll
        for (int st = 0; st < 8; ++st)
          acc[st][qt] = (f32x4){0.f, 0.f, 0.f, 0.f};
      }
    }
  }

  // merge the two s-halves (h=0,1) per q-column via LDS, then write
  __syncthreads();
  float* red = (float*)&sQh[0][0];   // 6 KiB, ring no longer needed
  if (quad == 0) {
#pragma unroll
    for (int qt = 0; qt < 4; ++qt) {
      int qq = g * 64 + qt * 16 + col;
      red[h * 256 + qq]        = mst[qt];
      red[512 + h * 256 + qq]  = se[qt];
      red[1024 + h * 256 + qq] = sel[qt];
    }
  }
  __syncthreads();
  if (h == 0 && quad == 0) {
#pragma unroll
    for (int qt = 0; qt < 4; ++qt) {
      int qq = g * 64 + qt * 16 + col;
      float m0 = red[qq],       m1 = red[256 + qq];
      float M  = fmaxf(m0, m1);
      float a0 = __expf(m0 - M), a1 = __expf(m1 - M);
      float SE  = red[512 + qq]  * a0 + red[512 + 256 + qq]  * a1;
      float SEL = red[1024 + qq] * a0 + red[1024 + 256 + qq] * a1;
      size_t qi = (size_t)b * LQ + q0 + qq;
      if (nsplit == 1) {
        out[qi] = SEL / SE;
      } else {
        pm[qi * NSPLIT + spl]   = M;
        pse[qi * NSPLIT + spl]  = SE;
        psel[qi * NSPLIT + spl] = SEL;
      }
    }
  }
}

__global__ __launch_bounds__(256) void combine_kernel(const float* __restrict__ pm,
                                                      const float* __restrict__ pse,
                                                      const float* __restrict__ psel,
                                                      float* __restrict__ out) {
  int i = blockIdx.x * blockDim.x + threadIdx.x;
  if (i >= B_ * LQ) return;
  float M = -INFINITY;
#pragma unroll
  for (int s = 0; s < NSPLIT; ++s) M = fmaxf(M, pm[i * NSPLIT + s]);
  float SE = 0.f, SEL = 0.f;
#pragma unroll
  for (int s = 0; s < NSPLIT; ++s) {
    float a = __expf(pm[i * NSPLIT + s] - M);
    SE  = fmaf(pse[i * NSPLIT + s],  a, SE);
    SEL = fmaf(psel[i * NSPLIT + s], a, SEL);
  }
  out[i] = SEL / SE;
}

// fp32 fallback (correctness insurance if ws too small)
__global__ __launch_bounds__(256) void fallback_kernel(const float* __restrict__ Q,
                                                       const float* __restrict__ S,
                                                       float* __restrict__ out) {
  __shared__ float qv[DD];
  __shared__ float red[256];
  const int b = blockIdx.y, qi = blockIdx.x, tid = threadIdx.x;
  const float* qrow = Q + ((size_t)b * LQ + qi) * DD;
  for (int d = tid; d < DD; d += 256) qv[d] = qrow[d];
  __syncthreads();
  const float* Sb = S + (size_t)b * LS * DD;
  float m = -INFINITY, se = 0.f, sel = 0.f;
  for (int s = tid; s < LS; s += 256) {
    const float* srow = Sb + (size_t)s * DD;
    float dot = 0.f;
    for (int d = 0; d < DD; ++d) dot = fmaf(qv[d], srow[d], dot);
    float mn = fmaxf(m, dot);
    float a = __expf(m - mn);
    float e = __expf(dot - mn);
    se  = se * a + e;
    sel = sel * a + e * dot;
    m = mn;
  }
  red[tid] = m; __syncthreads();
  for (int o = 128; o > 0; o >>= 1) { if (tid < o) red[tid] = fmaxf(red[tid], red[tid + o]); __syncthreads(); }
  float M = red[0]; __syncthreads();
  float a = __expf(m - M); se *= a; sel *= a;
  red[tid] = se; __syncthreads();
  for (int o = 128; o > 0; o >>= 1) { if (tid < o) red[tid] += red[tid + o]; __syncthreads(); }
  float SE = red[0]; __syncthreads();
  red[tid] = sel; __syncthreads();
  for (int o = 128; o > 0; o >>= 1) { if (tid < o) red[tid] += red[tid + o]; __syncthreads(); }
  float SEL = red[0];
  if (tid == 0) out[(size_t)b * LQ + qi] = SEL / SE;
}

extern "C" void kernel_launch(void* const* d_in, const int* in_sizes, int n_in,
                              void* d_out, int out_size, void* d_ws, size_t ws_size,
                              hipStream_t stream) {
  const float* Q = (const float*)d_in[0];
  const float* S = (const float*)d_in[1];
  float* out = (float*)d_out;
  const size_t nelem = (size_t)B_ * LQ * DD;                    // 16.78M / tensor
  const size_t need_base  = 2 * nelem * sizeof(unsigned short); // 67 MiB
  const size_t part_elems = (size_t)B_ * LQ * NSPLIT;
  const size_t need_split = need_base + 3 * part_elems * sizeof(float);

  if (ws_size >= need_base) {
    unsigned short* Qw = (unsigned short*)d_ws;
    unsigned short* Sw = Qw + nelem;
    cvt_kernel<<<2048, 256, 0, stream>>>(Q, S, Qw, Sw);
    if (ws_size >= need_split) {
      float* pm   = (float*)(Sw + nelem);
      float* pse  = pm + part_elems;
      float* psel = pse + part_elems;
      attn_kernel<<<dim3(LQ / BQ, B_, NSPLIT), 512, 0, stream>>>(Qw, Sw, out, pm, pse, psel, NSPLIT);
      combine_kernel<<<(B_ * LQ + 255) / 256, 256, 0, stream>>>(pm, pse, psel, out);
    } else {
      attn_kernel<<<dim3(LQ / BQ, B_, 1), 512, 0, stream>>>(Qw, Sw, out, nullptr, nullptr, nullptr, 1);
    }
  } else {
    fallback_kernel<<<dim3(LQ, B_), 256, 0, stream>>>(Q, S, out);
  }
}

// Round 9
// 220.763 us; speedup vs baseline: 1.0086x; 1.0086x over previous
//
#include <hip/hip_runtime.h>
#include <hip/hip_bf16.h>

#define B_  16
#define LQ  2048
#define LS  2048
#define DD  512
#define BQ  256
#define BS  256
#define BK  64
#define HK  32            // half-K granularity of the prefetch ring
#define NSB (LS / BS)     // 8 s-blocks total
#define NKC (DD / BK)     // 8 k-stages per s-block
#define NSPLIT 4

static_assert(NKC == 8, "stage>>3 math assumes NKC==8");

typedef short bf16x8 __attribute__((ext_vector_type(8)));
typedef float f32x4  __attribute__((ext_vector_type(4)));

// async global->LDS, 16B per lane. LDS dest = wave-uniform base + lane*16.
__device__ __forceinline__ void load_lds16(const void* g, void* l) {
  __builtin_amdgcn_global_load_lds((const __attribute__((address_space(1))) void*)g,
                                   (__attribute__((address_space(3))) void*)l,
                                   16, 0, 0);
}

__device__ __forceinline__ unsigned short f2bf(float f) {
  union { float f; unsigned int u; } v; v.f = f;
  unsigned int r = v.u + 0x7fffu + ((v.u >> 16) & 1u);  // RNE
  return (unsigned short)(r >> 16);
}

// Grid-stride cvt: 2048 blocks (first half Q, second half S), 16 iters each.
__global__ __launch_bounds__(256) void cvt_kernel(const float* __restrict__ Q,
                                                  const float* __restrict__ S,
                                                  unsigned short* __restrict__ Qw,
                                                  unsigned short* __restrict__ Sw) {
  const int half = gridDim.x >> 1;
  int blk = blockIdx.x;
  const float* src; unsigned short* dst;
  if (blk < half) { src = Q; dst = Qw; } else { src = S; dst = Sw; blk -= half; }
  const size_t n4 = (size_t)B_ * LQ * DD / 4;
  const size_t stride = (size_t)half * 256;
  for (size_t i = (size_t)blk * 256 + threadIdx.x; i < n4; i += stride) {
    float4 f = ((const float4*)src)[i];
    ushort4 u;
    u.x = f2bf(f.x); u.y = f2bf(f.y); u.z = f2bf(f.z); u.w = f2bf(f.w);
    ((ushort4*)dst)[i] = u;
  }
}

// score[b,q] = sum_s softmax(l)[s]*l[s],  l[s] = Q[b,q,:].S[b,s,:]
// MFMA 16x16x32: A = S-tile (M=s), B = Q-tile^T (N=q) -> C[row=s][col=q]
// C layout: col = lane&15, row = (lane>>4)*4 + reg  [m89/m91]
//
// Round-9: R8's ring (86us, best) shipped a 4-way LDS bank conflict (6.29M):
// with 64B rows (4 granules) the old slot-XOR (row&3) gives read position
// 4*(col&1) + (quad^(col&3)) -> only 4 positions per 16-lane quad-group ->
// 4-way. Fix: slot-XOR on (row>>1)&3. Read position becomes
// 4*(col&1) + (quad^((col>>1)&3)) -> (col&1,(col>>1)&3) covers 8 positions
// x2 lanes per quad-group = 2-way = free (same structure as the measured-0
// BK=64 pattern). Both sides changed together (staging chunk (l&3)^((l>>3)&3),
// read slot quad^((col>>1)&3)); frag-row bases are multiples of 16 so the
// base term drops out of s(row)=(row>>1)&3.
//
// Ring structure (R8, kept): 4-slot ring of K=32 halves, 3 in flight,
// vmcnt(8) at pair top (never 0 in-loop), one barrier per half, per half:
// {vmcnt(8); barrier; issue 4 gl_lds (u+3); 8 ds_read; lgkm0; 16 MFMA;
// 4 ds_read; lgkm0; 16 MFMA}. L2-locality lid decode (FETCH 33 MB),
// XCD chunk swizzle, grid-stride cvt kept.
__global__ __launch_bounds__(512, 2) void attn_kernel(const unsigned short* __restrict__ Qw,
                                                      const unsigned short* __restrict__ Sw,
                                                      float* __restrict__ out,
                                                      float* __restrict__ pm,
                                                      float* __restrict__ pse,
                                                      float* __restrict__ psel,
                                                      int nsplit) {
  // ring of 4 half-K slots, each 256 rows x 32 k x 2B = 16 KiB per tensor
  __shared__ __align__(16) unsigned short sQh[4][BQ * HK];  // 64 KiB
  __shared__ __align__(16) unsigned short sSh[4][BS * HK];  // 64 KiB

  // --- chunked XCD swizzle (bijective: nwg = 128*nsplit divisible by 8) ---
  const int pid = blockIdx.x + (blockIdx.y << 3) + (blockIdx.z << 7);
  const int nch = (nsplit << 7) >> 3;          // nwg / 8
  const int lid = (pid & 7) * nch + (pid >> 3);
  // locality decode: qb fastest, then spl, then b (per-XCD set ~4MB = L2)
  const int qb   = lid & 7;                    // gridDim.x == 8
  const int rest = lid >> 3;
  const int spl  = rest & (nsplit - 1);        // nsplit in {1,4}
  const int b    = rest >> (nsplit == 4 ? 2 : 0);

  const int tid  = threadIdx.x;
  const int w    = tid >> 6;      // 0..7
  const int lane = tid & 63;
  const int h    = w & 1;         // s-half: rows [h*128, h*128+128)
  const int g    = w >> 1;        // q-quarter: cols [g*64, g*64+64)
  const int col  = lane & 15;
  const int quad = lane >> 4;

  const int q0 = qb * BQ;
  const unsigned short* Qb = Qw + (size_t)b * LQ * DD;
  const unsigned short* Sb = Sw + (size_t)b * LS * DD;

  float mst[4] = { -INFINITY, -INFINITY, -INFINITY, -INFINITY };
  float se[4]  = { 0.f, 0.f, 0.f, 0.f };
  float sel[4] = { 0.f, 0.f, 0.f, 0.f };

  f32x4 acc[8][4];   // [s-tile][q-tile] = 128 regs (AGPR side of unified file)
#pragma unroll
  for (int st = 0; st < 8; ++st)
#pragma unroll
    for (int qt = 0; qt < 4; ++qt)
      acc[st][qt] = (f32x4){0.f, 0.f, 0.f, 0.f};

  // staging: lane l -> row (l>>2), slot (l&3); slot j of row r must hold
  // global chunk j ^ ((r>>1)&3) -> source chunk = (l&3) ^ ((l>>3)&3)
  const int cc8 = (((lane & 3) ^ ((lane >> 3) & 3)) * 8);
  const int rl  = lane >> 2;                 // row-within-16 for staging
  // read-side slot XOR: s(row) = (row>>1)&3 = (col>>1)&3 (bases %16 == 0)
  const int koq = ((quad ^ ((col >> 1) & 3)) * 8);

  const int sbs = spl * (NSB / nsplit);
  const int nst = (NSB / nsplit) * NKC;      // stages (K=64)
  const int U   = nst * 2;                   // halves (K=32)

  // waves 0..3 stage Q rows [w*64,+64); waves 4..7 stage S rows [(w-4)*64,+64)
  // 4 loads/wave/half, each load = 16 consecutive rows x 32k (1 KiB linear).
  auto issue_half = [&](int u) {
    const int t  = u >> 1;
    const int k0 = (t & 7) * 64 + (u & 1) * 32;
    const int slot = u & 3;
    if (w < 4) {
      const unsigned short* gp = Qb + (size_t)(q0 + w * 64 + rl) * DD + k0 + cc8;
      unsigned short* lp = &sQh[slot][(w * 64) * HK];
#pragma unroll
      for (int i = 0; i < 4; ++i)
        load_lds16(gp + (size_t)i * 16 * DD, lp + i * 16 * HK);
    } else {
      const int sb = sbs + (t >> 3);
      const unsigned short* gp = Sb + (size_t)(sb * BS + (w - 4) * 64 + rl) * DD + k0 + cc8;
      unsigned short* lp = &sSh[slot][((w - 4) * 64) * HK];
#pragma unroll
      for (int i = 0; i < 4; ++i)
        load_lds16(gp + (size_t)i * 16 * DD, lp + i * 16 * HK);
    }
  };

  // prologue: fill 3 ring slots
  issue_half(0); issue_half(1); issue_half(2);

#pragma unroll 1
  for (int u = 0; u < U; ++u) {
    // pair-top wait: own 4 loads of half u retired (u+1,u+2 keep flying)
    if (u < U - 2)       asm volatile("s_waitcnt vmcnt(8)" ::: "memory");
    else if (u == U - 2) asm volatile("s_waitcnt vmcnt(4)" ::: "memory");
    else                 asm volatile("s_waitcnt vmcnt(0)" ::: "memory");
    __builtin_amdgcn_s_barrier();             // half u visible CU-wide
    if (u + 3 < U) issue_half(u + 3);

    const unsigned short* bq = &sQh[u & 3][0];
    const unsigned short* bs = &sSh[u & 3][0];

    bf16x8 aq[4], asv[4];
#pragma unroll
    for (int qt = 0; qt < 4; ++qt)
      aq[qt] = *(const bf16x8*)&bq[(g * 64 + qt * 16 + col) * HK + koq];
#pragma unroll
    for (int st = 0; st < 4; ++st)
      asv[st] = *(const bf16x8*)&bs[(h * 128 + st * 16 + col) * HK + koq];
    asm volatile("s_waitcnt lgkmcnt(0)" ::: "memory");
    __builtin_amdgcn_sched_barrier(0);
    __builtin_amdgcn_s_setprio(1);
#pragma unroll
    for (int qt = 0; qt < 4; ++qt)
#pragma unroll
      for (int st = 0; st < 4; ++st)
        acc[st][qt] = __builtin_amdgcn_mfma_f32_16x16x32_bf16(asv[st], aq[qt], acc[st][qt], 0, 0, 0);
    __builtin_amdgcn_s_setprio(0);

#pragma unroll
    for (int st = 0; st < 4; ++st)
      asv[st] = *(const bf16x8*)&bs[(h * 128 + (4 + st) * 16 + col) * HK + koq];
    asm volatile("s_waitcnt lgkmcnt(0)" ::: "memory");
    __builtin_amdgcn_sched_barrier(0);
    __builtin_amdgcn_s_setprio(1);
#pragma unroll
    for (int qt = 0; qt < 4; ++qt)
#pragma unroll
      for (int st = 0; st < 4; ++st)
        acc[4 + st][qt] = __builtin_amdgcn_mfma_f32_16x16x32_bf16(asv[st], aq[qt], acc[4 + st][qt], 0, 0, 0);
    __builtin_amdgcn_s_setprio(0);

    if ((u & (2 * NKC - 1)) == 2 * NKC - 1) {
      // online softmax-weighted-mean over this wave's 128-s rows; runs while
      // 3 halves of the next s-block are in flight (no barrier until pair top)
#pragma unroll
      for (int qt = 0; qt < 4; ++qt) {
        float lmax = mst[qt];
#pragma unroll
        for (int st = 0; st < 8; ++st)
#pragma unroll
          for (int r = 0; r < 4; ++r)
            lmax = fmaxf(lmax, acc[st][qt][r]);
        lmax = fmaxf(lmax, __shfl_xor(lmax, 16, 64));
        lmax = fmaxf(lmax, __shfl_xor(lmax, 32, 64));
        float alpha = __expf(mst[qt] - lmax);  // exp(-inf)=0 on first block
        float pe = 0.f, pel = 0.f;
#pragma unroll
        for (int st = 0; st < 8; ++st)
#pragma unroll
          for (int r = 0; r < 4; ++r) {
            float l = acc[st][qt][r];
            float e = __expf(l - lmax);
            pe += e;
            pel = fmaf(e, l, pel);
          }
        pe  += __shfl_xor(pe, 16, 64);  pe  += __shfl_xor(pe, 32, 64);
        pel += __shfl_xor(pel, 16, 64); pel += __shfl_xor(pel, 32, 64);
        se[qt]  = fmaf(se[qt],  alpha, pe);
        sel[qt] = fmaf(sel[qt], alpha, pel);
        mst[qt] = lmax;
#pragma unroll
        for (int st = 0; st < 8; ++st)
          acc[st][qt] = (f32x4){0.f, 0.f, 0.f, 0.f};
      }
    }
  }

  // merge the two s-halves (h=0,1) per q-column via LDS, then write
  __syncthreads();
  float* red = (float*)&sQh[0][0];   // 6 KiB, ring no longer needed
  if (quad == 0) {
#pragma unroll
    for (int qt = 0; qt < 4; ++qt) {
      int qq = g * 64 + qt * 16 + col;
      red[h * 256 + qq]        = mst[qt];
      red[512 + h * 256 + qq]  = se[qt];
      red[1024 + h * 256 + qq] = sel[qt];
    }
  }
  __syncthreads();
  if (h == 0 && quad == 0) {
#pragma unroll
    for (int qt = 0; qt < 4; ++qt) {
      int qq = g * 64 + qt * 16 + col;
      float m0 = red[qq],       m1 = red[256 + qq];
      float M  = fmaxf(m0, m1);
      float a0 = __expf(m0 - M), a1 = __expf(m1 - M);
      float SE  = red[512 + qq]  * a0 + red[512 + 256 + qq]  * a1;
      float SEL = red[1024 + qq] * a0 + red[1024 + 256 + qq] * a1;
      size_t qi = (size_t)b * LQ + q0 + qq;
      if (nsplit == 1) {
        out[qi] = SEL / SE;
      } else {
        pm[qi * NSPLIT + spl]   = M;
        pse[qi * NSPLIT + spl]  = SE;
        psel[qi * NSPLIT + spl] = SEL;
      }
    }
  }
}

__global__ __launch_bounds__(256) void combine_kernel(const float* __restrict__ pm,
                                                      const float* __restrict__ pse,
                                                      const float* __restrict__ psel,
                                                      float* __restrict__ out) {
  int i = blockIdx.x * blockDim.x + threadIdx.x;
  if (i >= B_ * LQ) return;
  float M = -INFINITY;
#pragma unroll
  for (int s = 0; s < NSPLIT; ++s) M = fmaxf(M, pm[i * NSPLIT + s]);
  float SE = 0.f, SEL = 0.f;
#pragma unroll
  for (int s = 0; s < NSPLIT; ++s) {
    float a = __expf(pm[i * NSPLIT + s] - M);
    SE  = fmaf(pse[i * NSPLIT + s],  a, SE);
    SEL = fmaf(psel[i * NSPLIT + s], a, SEL);
  }
  out[i] = SEL / SE;
}

// fp32 fallback (correctness insurance if ws too small)
__global__ __launch_bounds__(256) void fallback_kernel(const float* __restrict__ Q,
                                                       const float* __restrict__ S,
                                                       float* __restrict__ out) {
  __shared__ float qv[DD];
  __shared__ float red[256];
  const int b = blockIdx.y, qi = blockIdx.x, tid = threadIdx.x;
  const float* qrow = Q + ((size_t)b * LQ + qi) * DD;
  for (int d = tid; d < DD; d += 256) qv[d] = qrow[d];
  __syncthreads();
  const float* Sb = S + (size_t)b * LS * DD;
  float m = -INFINITY, se = 0.f, sel = 0.f;
  for (int s = tid; s < LS; s += 256) {
    const float* srow = Sb + (size_t)s * DD;
    float dot = 0.f;
    for (int d = 0; d < DD; ++d) dot = fmaf(qv[d], srow[d], dot);
    float mn = fmaxf(m, dot);
    float a = __expf(m - mn);
    float e = __expf(dot - mn);
    se  = se * a + e;
    sel = sel * a + e * dot;
    m = mn;
  }
  red[tid] = m; __syncthreads();
  for (int o = 128; o > 0; o >>= 1) { if (tid < o) red[tid] = fmaxf(red[tid], red[tid + o]); __syncthreads(); }
  float M = red[0]; __syncthreads();
  float a = __expf(m - M); se *= a; sel *= a;
  red[tid] = se; __syncthreads();
  for (int o = 128; o > 0; o >>= 1) { if (tid < o) red[tid] += red[tid + o]; __syncthreads(); }
  float SE = red[0]; __syncthreads();
  red[tid] = sel; __syncthreads();
  for (int o = 128; o > 0; o >>= 1) { if (tid < o) red[tid] += red[tid + o]; __syncthreads(); }
  float SEL = red[0];
  if (tid == 0) out[(size_t)b * LQ + qi] = SEL / SE;
}

extern "C" void kernel_launch(void* const* d_in, const int* in_sizes, int n_in,
                              void* d_out, int out_size, void* d_ws, size_t ws_size,
                              hipStream_t stream) {
  const float* Q = (const float*)d_in[0];
  const float* S = (const float*)d_in[1];
  float* out = (float*)d_out;
  const size_t nelem = (size_t)B_ * LQ * DD;                    // 16.78M / tensor
  const size_t need_base  = 2 * nelem * sizeof(unsigned short); // 67 MiB
  const size_t part_elems = (size_t)B_ * LQ * NSPLIT;
  const size_t need_split = need_base + 3 * part_elems * sizeof(float);

  if (ws_size >= need_base) {
    unsigned short* Qw = (unsigned short*)d_ws;
    unsigned short* Sw = Qw + nelem;
    cvt_kernel<<<2048, 256, 0, stream>>>(Q, S, Qw, Sw);
    if (ws_size >= need_split) {
      float* pm   = (float*)(Sw + nelem);
      float* pse  = pm + part_elems;
      float* psel = pse + part_elems;
      attn_kernel<<<dim3(LQ / BQ, B_, NSPLIT), 512, 0, stream>>>(Qw, Sw, out, pm, pse, psel, NSPLIT);
      combine_kernel<<<(B_ * LQ + 255) / 256, 256, 0, stream>>>(pm, pse, psel, out);
    } else {
      attn_kernel<<<dim3(LQ / BQ, B_, 1), 512, 0, stream>>>(Qw, Sw, out, nullptr, nullptr, nullptr, 1);
    }
  } else {
    fallback_kernel<<<dim3(LQ, B_), 256, 0, stream>>>(Q, S, out);
  }
}